// Round 3
// baseline (16877.335 us; speedup 1.0000x reference)
//
#include <hip/hip_runtime.h>
#include <float.h>

#define N_PTS 16384
#define M_PTS 4096
#define K_NN  16
#define CIN   64
#define COUT  64

typedef float v2f __attribute__((ext_vector_type(2)));

// Exact f32 rounding to match numpy/jax: ((dx*dx + dy*dy) + dz*dz), no fma contraction.
__device__ __forceinline__ float dist2_exact(float ax, float ay, float az,
                                             float bx, float by, float bz) {
    float dx = __fsub_rn(ax, bx);
    float dy = __fsub_rn(ay, by);
    float dz = __fsub_rn(az, bz);
    return __fadd_rn(__fadd_rn(__fmul_rn(dx, dx), __fmul_rn(dy, dy)), __fmul_rn(dz, dz));
}

// ---- DPP wave-64 reduction steps (idempotent ops -> full masks safe; bound_ctrl
// false returns `old` for invalid lanes = own value) ----
template <int CTRL>
__device__ __forceinline__ float dpp_fmax_step(float x) {
    int xi = __float_as_int(x);
    int yi = __builtin_amdgcn_update_dpp(xi, xi, CTRL, 0xf, 0xf, false);
    return fmaxf(x, __int_as_float(yi));
}
template <int CTRL>
__device__ __forceinline__ unsigned dpp_umin_step(unsigned x) {
    int xi = (int)x;
    unsigned y = (unsigned)__builtin_amdgcn_update_dpp(xi, xi, CTRL, 0xf, 0xf, false);
    return y < x ? y : x;
}

__device__ __forceinline__ float wave_fmax(float x) {
    x = dpp_fmax_step<0x111>(x);   // row_shr:1
    x = dpp_fmax_step<0x112>(x);   // row_shr:2
    x = dpp_fmax_step<0x114>(x);   // row_shr:4
    x = dpp_fmax_step<0x118>(x);   // row_shr:8
    x = dpp_fmax_step<0x142>(x);   // row_bcast:15
    x = dpp_fmax_step<0x143>(x);   // row_bcast:31
    return __int_as_float(__builtin_amdgcn_readlane(__float_as_int(x), 63));
}
__device__ __forceinline__ unsigned wave_umin(unsigned x) {
    x = dpp_umin_step<0x111>(x);
    x = dpp_umin_step<0x112>(x);
    x = dpp_umin_step<0x114>(x);
    x = dpp_umin_step<0x118>(x);
    x = dpp_umin_step<0x142>(x);
    x = dpp_umin_step<0x143>(x);
    return (unsigned)__builtin_amdgcn_readlane((int)x, 63);
}

// ---------------------------------------------------------------------------
// Kernel 1: furthest point sampling. Single block, 1024 threads, 16 pts/thread
// as packed v2f32 pairs in registers. Value-only reductions; index recovered
// lazily by the (usually unique) candidate wave; winner coords come from the
// winner's REGISTERS via LDS — no global loads inside the loop.
// ---------------------------------------------------------------------------
__global__ __launch_bounds__(1024, 4) void fps_kernel(const float* __restrict__ p,
                                                      float* __restrict__ out) {
#pragma clang fp contract(off)
    const int t = threadIdx.x;
    const int lane = t & 63, wv = t >> 6;
    __shared__ float s_wmax[2][16];
    __shared__ float s_cq[16][4];
    __shared__ unsigned long long s_key[2];

    v2f px[8], py[8], pz[8], d2[8];
    const float q0x = p[0], q0y = p[1], q0z = p[2];
    float bv = -1.0f;
#pragma unroll
    for (int u = 0; u < 8; ++u) {
        const int j0 = (2 * u) * 1024 + t;
        const int j1 = j0 + 1024;
        const float ax0 = p[3 * j0], ay0 = p[3 * j0 + 1], az0 = p[3 * j0 + 2];
        const float ax1 = p[3 * j1], ay1 = p[3 * j1 + 1], az1 = p[3 * j1 + 2];
        px[u] = (v2f){ax0, ax1};
        py[u] = (v2f){ay0, ay1};
        pz[u] = (v2f){az0, az1};
        d2[u] = (v2f){dist2_exact(ax0, ay0, az0, q0x, q0y, q0z),
                      dist2_exact(ax1, ay1, az1, q0x, q0y, q0z)};
        bv = fmaxf(bv, fmaxf(d2[u].x, d2[u].y));
    }
    if (t == 0) {
        out[0] = q0x; out[1] = q0y; out[2] = q0z;      // n_p[0] = p[0]
        out[12288 + 786432] = 4096.0f;                 // n_o scalar
        s_key[0] = 0ull; s_key[1] = 0ull;
    }

    for (int i = 1; i < M_PTS; ++i) {
        const int par = i & 1;
        // per-wave max of bv; lane63-valid, broadcast to sgpr
        float wval = bv;
        wval = dpp_fmax_step<0x111>(wval);
        wval = dpp_fmax_step<0x112>(wval);
        wval = dpp_fmax_step<0x114>(wval);
        wval = dpp_fmax_step<0x118>(wval);
        wval = dpp_fmax_step<0x142>(wval);
        wval = dpp_fmax_step<0x143>(wval);
        const float wmax_u = __int_as_float(__builtin_amdgcn_readlane(__float_as_int(wval), 63));
        if (lane == 63) s_wmax[par][wv] = wval;
        if (t == 0) s_key[1 - par] = 0ull;             // reset for NEXT iteration
        __syncthreads();                               // barrier 1

        // cross-wave value max: 16 floats, 4 row_shr steps within 16-lane rows
        float cv = s_wmax[par][lane & 15];
        cv = dpp_fmax_step<0x111>(cv);
        cv = dpp_fmax_step<0x112>(cv);
        cv = dpp_fmax_step<0x114>(cv);
        cv = dpp_fmax_step<0x118>(cv);
        const float vmax = __int_as_float(__builtin_amdgcn_readlane(__float_as_int(cv), 63));

        // lazy index resolution: only wave(s) holding the global max scan
        if (wmax_u == vmax) {
            unsigned idx = 0x7fffffffu;
#pragma unroll
            for (int u = 15; u >= 0; --u) {            // descending: smallest u wins
                const float dv = (u & 1) ? d2[u >> 1].y : d2[u >> 1].x;
                if (dv == vmax) idx = (unsigned)(u * 1024 + t);
            }
            const unsigned wmin = wave_umin(idx);
            if (idx == wmin) {                         // unique winner lane
                const int u = (int)(wmin >> 10);
                const float qx = (u & 1) ? px[u >> 1].y : px[u >> 1].x;
                const float qy = (u & 1) ? py[u >> 1].y : py[u >> 1].x;
                const float qz = (u & 1) ? pz[u >> 1].y : pz[u >> 1].x;
                s_cq[wv][0] = qx; s_cq[wv][1] = qy; s_cq[wv][2] = qz;
                const unsigned long long key =
                    ((unsigned long long)__float_as_uint(vmax) << 32) |
                    (unsigned long long)(~wmin);       // bigger key = smaller idx
                atomicMax(&s_key[par], key);
            }
        }
        __syncthreads();                               // barrier 2

        const unsigned long long key = s_key[par];
        const unsigned wmin_g = ~((unsigned)key);
        const int wwin = (int)((wmin_g & 1023u) >> 6);
        const float qx = s_cq[wwin][0];
        const float qy = s_cq[wwin][1];
        const float qz = s_cq[wwin][2];
        if (t == 0) { out[3 * i] = qx; out[3 * i + 1] = qy; out[3 * i + 2] = qz; }

        // packed min-update + fused running max (v_pk_* + v_max3_f32)
        const v2f qx2 = (v2f){qx, qx};
        const v2f qy2 = (v2f){qy, qy};
        const v2f qz2 = (v2f){qz, qz};
        bv = -1.0f;
#pragma unroll
        for (int u = 0; u < 8; ++u) {
            const v2f dx = px[u] - qx2;
            const v2f dy = py[u] - qy2;
            const v2f dz = pz[u] - qz2;
            const v2f m1 = dx * dx;
            const v2f m2 = dy * dy;
            const v2f m3 = dz * dz;
            const v2f s = (m1 + m2) + m3;              // contract(off): matches reference
            d2[u] = __builtin_elementwise_min(d2[u], s);
            bv = fmaxf(bv, fmaxf(d2[u].x, d2[u].y));   // v_max3
        }
    }
}

// ---------------------------------------------------------------------------
// Kernel 2: kNN (k=16) of each n_p among p. One wave per query, per-lane sorted
// top-16 in registers, lexicographic (d, idx) wave merge (matches top_k ties).
// ---------------------------------------------------------------------------
__global__ __launch_bounds__(256) void knn_kernel(const float* __restrict__ p,
                                                  const float* __restrict__ np_,
                                                  int* __restrict__ nn) {
    const int lane = threadIdx.x & 63;
    const int m = (blockIdx.x * 256 + threadIdx.x) >> 6;
    if (m >= M_PTS) return;

    const float qx = np_[3 * m], qy = np_[3 * m + 1], qz = np_[3 * m + 2];
    const float qq = __fadd_rn(__fadd_rn(__fmul_rn(qx, qx), __fmul_rn(qy, qy)),
                               __fmul_rn(qz, qz));
    float D[16]; int I[16];
#pragma unroll
    for (int s = 0; s < 16; ++s) { D[s] = FLT_MAX; I[s] = 0x7fffffff; }

    for (int c = 0; c < N_PTS / 64; ++c) {
        const int j = c * 64 + lane;
        const float px = p[3 * j], py = p[3 * j + 1], pz = p[3 * j + 2];
        const float pp = __fadd_rn(__fadd_rn(__fmul_rn(px, px), __fmul_rn(py, py)),
                                   __fmul_rn(pz, pz));
        const float qp = __fadd_rn(__fadd_rn(__fmul_rn(qx, px), __fmul_rn(qy, py)),
                                   __fmul_rn(qz, pz));
        const float d = __fadd_rn(__fsub_rn(qq, __fmul_rn(2.0f, qp)), pp);
        if (d < D[15]) {
            D[15] = d; I[15] = j;
#pragma unroll
            for (int s = 15; s > 0; --s) {
                if (D[s] < D[s - 1]) {
                    float tf = D[s]; D[s] = D[s - 1]; D[s - 1] = tf;
                    int   ti = I[s]; I[s] = I[s - 1]; I[s - 1] = ti;
                }
            }
        }
    }

    int myout = 0;
    for (int r = 0; r < 16; ++r) {
        float v = D[0]; int ix = I[0]; int bl = lane;
#pragma unroll
        for (int off = 1; off < 64; off <<= 1) {
            float ov = __shfl_xor(v, off);
            int   oi = __shfl_xor(ix, off);
            int   ol = __shfl_xor(bl, off);
            if (ov < v || (ov == v && oi < ix)) { v = ov; ix = oi; bl = ol; }
        }
        if (lane == bl) {
#pragma unroll
            for (int s = 0; s < 15; ++s) { D[s] = D[s + 1]; I[s] = I[s + 1]; }
            D[15] = FLT_MAX; I[15] = 0x7fffffff;
        }
        if (lane == r) myout = ix;
    }
    if (lane < K_NN) nn[m * K_NN + lane] = myout;
}

// ---------------------------------------------------------------------------
// Kernel 3: grouped VNLinearLeakyReLU + mean over nsample.
// One block per query m. W_feat/W_dir staged transposed in LDS; thread (o,i)
// accumulates over k. out layout (Cout,3,M): out[(o*3+i)*M + m].
// ---------------------------------------------------------------------------
__global__ __launch_bounds__(256) void vn_kernel(const float* __restrict__ x,
                                                 const float* __restrict__ Wf,
                                                 const float* __restrict__ Wd,
                                                 const int* __restrict__ nn,
                                                 float* __restrict__ out) {
    __shared__ float sWf[CIN * COUT];
    __shared__ float sWd[CIN * COUT];
    __shared__ float sg[CIN * 3];
    __shared__ float sq[COUT * 3];
    __shared__ float sd[COUT * 3];
    __shared__ float sf[COUT];

    const int m = blockIdx.x;
    const int tid = threadIdx.x;
    for (int u = tid; u < CIN * COUT; u += 256) {
        const int o = u >> 6, c = u & 63;
        sWf[c * 64 + o] = Wf[u];
        sWd[c * 64 + o] = Wd[u];
    }
    const int o = tid & 63, i = tid >> 6;
    const bool active = tid < 192;
    float acc = 0.0f;

    for (int k = 0; k < K_NN; ++k) {
        __syncthreads();
        const int j = nn[m * K_NN + k];
        if (tid < 192) sg[tid] = x[j * 192 + tid];
        __syncthreads();
        float qv = 0.0f, dv = 0.0f;
        if (active) {
#pragma unroll
            for (int c = 0; c < CIN; ++c) {
                const float g = sg[c * 3 + i];
                qv = fmaf(sWf[c * 64 + o], g, qv);
                dv = fmaf(sWd[c * 64 + o], g, dv);
            }
            sq[o * 3 + i] = qv;
            sd[o * 3 + i] = dv;
        }
        __syncthreads();
        if (tid < 64) {
            const float d0 = sd[tid * 3], d1 = sd[tid * 3 + 1], d2v = sd[tid * 3 + 2];
            const float q0 = sq[tid * 3], q1 = sq[tid * 3 + 1], q2 = sq[tid * 3 + 2];
            const float dot = q0 * d0 + q1 * d1 + q2 * d2v;
            const float dns = d0 * d0 + d1 * d1 + d2v * d2v + 1e-6f;
            sf[tid] = (dot >= 0.0f) ? 0.0f : 0.8f * (dot / dns);
        }
        __syncthreads();
        if (active) acc += qv - sf[o] * dv;
    }
    if (active) out[(o * 3 + i) * M_PTS + m] = acc * 0.0625f;
}

// ---------------------------------------------------------------------------
extern "C" void kernel_launch(void* const* d_in, const int* in_sizes, int n_in,
                              void* d_out, int out_size, void* d_ws, size_t ws_size,
                              hipStream_t stream) {
    const float* p  = (const float*)d_in[0];
    const float* x  = (const float*)d_in[1];
    const float* Wf = (const float*)d_in[2];
    const float* Wd = (const float*)d_in[3];
    float* out = (float*)d_out;
    int* nn = (int*)d_ws;

    fps_kernel<<<1, 1024, 0, stream>>>(p, out);
    knn_kernel<<<M_PTS / 4, 256, 0, stream>>>(p, out, nn);
    vn_kernel<<<M_PTS, 256, 0, stream>>>(x, Wf, Wd, nn, out + 12288);
}

// Round 4
// 8328.687 us; speedup vs baseline: 2.0264x; 2.0264x over previous
//
#include <hip/hip_runtime.h>
#include <float.h>

#define N_PTS 16384
#define M_PTS 4096
#define K_NN  16
#define CIN   64
#define COUT  64

typedef float v2f __attribute__((ext_vector_type(2)));

// Exact f32 rounding to match numpy/jax: ((dx*dx + dy*dy) + dz*dz), no fma contraction.
__device__ __forceinline__ float dist2_exact(float ax, float ay, float az,
                                             float bx, float by, float bz) {
    float dx = __fsub_rn(ax, bx);
    float dy = __fsub_rn(ay, by);
    float dz = __fsub_rn(az, bz);
    return __fadd_rn(__fadd_rn(__fmul_rn(dx, dx), __fmul_rn(dy, dy)), __fmul_rn(dz, dz));
}

// ---- DPP wave-64 reduction steps (idempotent ops -> full masks safe) ----
template <int CTRL>
__device__ __forceinline__ float dpp_fmax_step(float x) {
    int xi = __float_as_int(x);
    int yi = __builtin_amdgcn_update_dpp(xi, xi, CTRL, 0xf, 0xf, false);
    return fmaxf(x, __int_as_float(yi));
}
template <int CTRL>
__device__ __forceinline__ unsigned dpp_umin_step(unsigned x) {
    int xi = (int)x;
    unsigned y = (unsigned)__builtin_amdgcn_update_dpp(xi, xi, CTRL, 0xf, 0xf, false);
    return y < x ? y : x;
}
__device__ __forceinline__ unsigned wave_umin(unsigned x) {
    x = dpp_umin_step<0x111>(x);
    x = dpp_umin_step<0x112>(x);
    x = dpp_umin_step<0x114>(x);
    x = dpp_umin_step<0x118>(x);
    x = dpp_umin_step<0x142>(x);
    x = dpp_umin_step<0x143>(x);
    return (unsigned)__builtin_amdgcn_readlane((int)x, 63);
}

// ---------------------------------------------------------------------------
// Kernel 1: furthest point sampling. Single block, 1024 threads, 16 pts/thread
// as packed v2f32 pairs in registers. Value-only reductions; index + winner
// coords recovered lazily by the candidate wave using ONLY compile-time
// register indices (dynamic indexing spills the whole state to scratch — R3).
// ---------------------------------------------------------------------------
__global__ __launch_bounds__(1024, 4) void fps_kernel(const float* __restrict__ p,
                                                      float* __restrict__ out) {
#pragma clang fp contract(off)
    const int t = threadIdx.x;
    const int lane = t & 63, wv = t >> 6;
    __shared__ float s_wmax[2][16];
    __shared__ float s_cq[16][4];
    __shared__ unsigned long long s_key[2];

    v2f px[8], py[8], pz[8], d2[8];
    const float q0x = p[0], q0y = p[1], q0z = p[2];
    float bv = -1.0f;
#pragma unroll
    for (int u = 0; u < 8; ++u) {
        const int j0 = (2 * u) * 1024 + t;
        const int j1 = j0 + 1024;
        const float ax0 = p[3 * j0], ay0 = p[3 * j0 + 1], az0 = p[3 * j0 + 2];
        const float ax1 = p[3 * j1], ay1 = p[3 * j1 + 1], az1 = p[3 * j1 + 2];
        px[u] = (v2f){ax0, ax1};
        py[u] = (v2f){ay0, ay1};
        pz[u] = (v2f){az0, az1};
        d2[u] = (v2f){dist2_exact(ax0, ay0, az0, q0x, q0y, q0z),
                      dist2_exact(ax1, ay1, az1, q0x, q0y, q0z)};
        bv = fmaxf(bv, fmaxf(d2[u].x, d2[u].y));
    }
    if (t == 0) {
        out[0] = q0x; out[1] = q0y; out[2] = q0z;      // n_p[0] = p[0]
        out[12288 + 786432] = 4096.0f;                 // n_o scalar
        s_key[0] = 0ull; s_key[1] = 0ull;
    }

    for (int i = 1; i < M_PTS; ++i) {
        const int par = i & 1;
        // per-wave max of bv (6 DPP steps), lane63 -> sgpr broadcast
        float wval = bv;
        wval = dpp_fmax_step<0x111>(wval);
        wval = dpp_fmax_step<0x112>(wval);
        wval = dpp_fmax_step<0x114>(wval);
        wval = dpp_fmax_step<0x118>(wval);
        wval = dpp_fmax_step<0x142>(wval);
        wval = dpp_fmax_step<0x143>(wval);
        const float wmax_u = __int_as_float(__builtin_amdgcn_readlane(__float_as_int(wval), 63));
        if (lane == 63) s_wmax[par][wv] = wval;
        if (t == 0) s_key[1 - par] = 0ull;             // reset for NEXT iteration
        __syncthreads();                               // barrier 1

        // cross-wave value max: 16 floats, 4 row_shr steps within 16-lane rows
        float cv = s_wmax[par][lane & 15];
        cv = dpp_fmax_step<0x111>(cv);
        cv = dpp_fmax_step<0x112>(cv);
        cv = dpp_fmax_step<0x114>(cv);
        cv = dpp_fmax_step<0x118>(cv);
        const float vmax = __int_as_float(__builtin_amdgcn_readlane(__float_as_int(cv), 63));

        // lazy index + coord resolution: only wave(s) holding the global max.
        // ALL register indices below are compile-time (unrolled) — no scratch.
        if (wmax_u == vmax) {
            unsigned idx = 0x7fffffffu;
            float cqx = 0.0f, cqy = 0.0f, cqz = 0.0f;
#pragma unroll
            for (int u = 15; u >= 0; --u) {            // descending: smallest u wins
                const float dv = (u & 1) ? d2[u >> 1].y : d2[u >> 1].x;
                if (dv == vmax) {
                    idx = (unsigned)(u * 1024 + t);
                    cqx = (u & 1) ? px[u >> 1].y : px[u >> 1].x;
                    cqy = (u & 1) ? py[u >> 1].y : py[u >> 1].x;
                    cqz = (u & 1) ? pz[u >> 1].y : pz[u >> 1].x;
                }
            }
            const unsigned wmin = wave_umin(idx);
            if (idx == wmin) {                         // unique winner lane
                s_cq[wv][0] = cqx; s_cq[wv][1] = cqy; s_cq[wv][2] = cqz;
                const unsigned long long key =
                    ((unsigned long long)__float_as_uint(vmax) << 32) |
                    (unsigned long long)(~wmin);       // bigger key = smaller idx
                atomicMax(&s_key[par], key);
            }
        }
        __syncthreads();                               // barrier 2

        const unsigned wmin_g = ~((unsigned)s_key[par]);
        const int wwin = (int)((wmin_g & 1023u) >> 6);
        const float qx = s_cq[wwin][0];
        const float qy = s_cq[wwin][1];
        const float qz = s_cq[wwin][2];
        if (t == 0) { out[3 * i] = qx; out[3 * i + 1] = qy; out[3 * i + 2] = qz; }

        // packed min-update + fused running max
        const v2f qx2 = (v2f){qx, qx};
        const v2f qy2 = (v2f){qy, qy};
        const v2f qz2 = (v2f){qz, qz};
        bv = -1.0f;
#pragma unroll
        for (int u = 0; u < 8; ++u) {
            const v2f dx = px[u] - qx2;
            const v2f dy = py[u] - qy2;
            const v2f dz = pz[u] - qz2;
            const v2f m1 = dx * dx;
            const v2f m2 = dy * dy;
            const v2f m3 = dz * dz;
            const v2f s = (m1 + m2) + m3;              // contract(off): matches reference
            d2[u] = __builtin_elementwise_min(d2[u], s);
            bv = fmaxf(bv, fmaxf(d2[u].x, d2[u].y));
        }
    }
}

// ---------------------------------------------------------------------------
// Kernel 2: kNN (k=16) of each n_p among p. One wave per query, per-lane sorted
// top-16 in registers, lexicographic (d, idx) wave merge (matches top_k ties).
// ---------------------------------------------------------------------------
__global__ __launch_bounds__(256) void knn_kernel(const float* __restrict__ p,
                                                  const float* __restrict__ np_,
                                                  int* __restrict__ nn) {
    const int lane = threadIdx.x & 63;
    const int m = (blockIdx.x * 256 + threadIdx.x) >> 6;
    if (m >= M_PTS) return;

    const float qx = np_[3 * m], qy = np_[3 * m + 1], qz = np_[3 * m + 2];
    const float qq = __fadd_rn(__fadd_rn(__fmul_rn(qx, qx), __fmul_rn(qy, qy)),
                               __fmul_rn(qz, qz));
    float D[16]; int I[16];
#pragma unroll
    for (int s = 0; s < 16; ++s) { D[s] = FLT_MAX; I[s] = 0x7fffffff; }

    for (int c = 0; c < N_PTS / 64; ++c) {
        const int j = c * 64 + lane;
        const float px = p[3 * j], py = p[3 * j + 1], pz = p[3 * j + 2];
        const float pp = __fadd_rn(__fadd_rn(__fmul_rn(px, px), __fmul_rn(py, py)),
                                   __fmul_rn(pz, pz));
        const float qp = __fadd_rn(__fadd_rn(__fmul_rn(qx, px), __fmul_rn(qy, py)),
                                   __fmul_rn(qz, pz));
        const float d = __fadd_rn(__fsub_rn(qq, __fmul_rn(2.0f, qp)), pp);
        if (d < D[15]) {
            D[15] = d; I[15] = j;
#pragma unroll
            for (int s = 15; s > 0; --s) {
                if (D[s] < D[s - 1]) {
                    float tf = D[s]; D[s] = D[s - 1]; D[s - 1] = tf;
                    int   ti = I[s]; I[s] = I[s - 1]; I[s - 1] = ti;
                }
            }
        }
    }

    int myout = 0;
    for (int r = 0; r < 16; ++r) {
        float v = D[0]; int ix = I[0]; int bl = lane;
#pragma unroll
        for (int off = 1; off < 64; off <<= 1) {
            float ov = __shfl_xor(v, off);
            int   oi = __shfl_xor(ix, off);
            int   ol = __shfl_xor(bl, off);
            if (ov < v || (ov == v && oi < ix)) { v = ov; ix = oi; bl = ol; }
        }
        if (lane == bl) {
#pragma unroll
            for (int s = 0; s < 15; ++s) { D[s] = D[s + 1]; I[s] = I[s + 1]; }
            D[15] = FLT_MAX; I[15] = 0x7fffffff;
        }
        if (lane == r) myout = ix;
    }
    if (lane < K_NN) nn[m * K_NN + lane] = myout;
}

// ---------------------------------------------------------------------------
// Kernel 3: grouped VNLinearLeakyReLU + mean over nsample.
// One block per query m. W_feat/W_dir staged transposed in LDS; thread (o,i)
// accumulates over k. out layout (Cout,3,M): out[(o*3+i)*M + m].
// ---------------------------------------------------------------------------
__global__ __launch_bounds__(256) void vn_kernel(const float* __restrict__ x,
                                                 const float* __restrict__ Wf,
                                                 const float* __restrict__ Wd,
                                                 const int* __restrict__ nn,
                                                 float* __restrict__ out) {
    __shared__ float sWf[CIN * COUT];
    __shared__ float sWd[CIN * COUT];
    __shared__ float sg[CIN * 3];
    __shared__ float sq[COUT * 3];
    __shared__ float sd[COUT * 3];
    __shared__ float sf[COUT];

    const int m = blockIdx.x;
    const int tid = threadIdx.x;
    for (int u = tid; u < CIN * COUT; u += 256) {
        const int o = u >> 6, c = u & 63;
        sWf[c * 64 + o] = Wf[u];
        sWd[c * 64 + o] = Wd[u];
    }
    const int o = tid & 63, i = tid >> 6;
    const bool active = tid < 192;
    float acc = 0.0f;

    for (int k = 0; k < K_NN; ++k) {
        __syncthreads();
        const int j = nn[m * K_NN + k];
        if (tid < 192) sg[tid] = x[j * 192 + tid];
        __syncthreads();
        float qv = 0.0f, dv = 0.0f;
        if (active) {
#pragma unroll
            for (int c = 0; c < CIN; ++c) {
                const float g = sg[c * 3 + i];
                qv = fmaf(sWf[c * 64 + o], g, qv);
                dv = fmaf(sWd[c * 64 + o], g, dv);
            }
            sq[o * 3 + i] = qv;
            sd[o * 3 + i] = dv;
        }
        __syncthreads();
        if (tid < 64) {
            const float d0 = sd[tid * 3], d1 = sd[tid * 3 + 1], d2v = sd[tid * 3 + 2];
            const float q0 = sq[tid * 3], q1 = sq[tid * 3 + 1], q2 = sq[tid * 3 + 2];
            const float dot = q0 * d0 + q1 * d1 + q2 * d2v;
            const float dns = d0 * d0 + d1 * d1 + d2v * d2v + 1e-6f;
            sf[tid] = (dot >= 0.0f) ? 0.0f : 0.8f * (dot / dns);
        }
        __syncthreads();
        if (active) acc += qv - sf[o] * dv;
    }
    if (active) out[(o * 3 + i) * M_PTS + m] = acc * 0.0625f;
}

// ---------------------------------------------------------------------------
extern "C" void kernel_launch(void* const* d_in, const int* in_sizes, int n_in,
                              void* d_out, int out_size, void* d_ws, size_t ws_size,
                              hipStream_t stream) {
    const float* p  = (const float*)d_in[0];
    const float* x  = (const float*)d_in[1];
    const float* Wf = (const float*)d_in[2];
    const float* Wd = (const float*)d_in[3];
    float* out = (float*)d_out;
    int* nn = (int*)d_ws;

    fps_kernel<<<1, 1024, 0, stream>>>(p, out);
    knn_kernel<<<M_PTS / 4, 256, 0, stream>>>(p, out, nn);
    vn_kernel<<<M_PTS, 256, 0, stream>>>(x, Wf, Wd, nn, out + 12288);
}

// Round 5
// 8042.830 us; speedup vs baseline: 2.0984x; 1.0355x over previous
//
#include <hip/hip_runtime.h>
#include <float.h>

#define N_PTS 16384
#define M_PTS 4096
#define K_NN  16
#define CIN   64
#define COUT  64

typedef float v2f __attribute__((ext_vector_type(2)));

// Exact f32 rounding to match numpy/jax: ((dx*dx + dy*dy) + dz*dz), no fma contraction.
__device__ __forceinline__ float dist2_exact(float ax, float ay, float az,
                                             float bx, float by, float bz) {
    float dx = __fsub_rn(ax, bx);
    float dy = __fsub_rn(ay, by);
    float dz = __fsub_rn(az, bz);
    return __fadd_rn(__fadd_rn(__fmul_rn(dx, dx), __fmul_rn(dy, dy)), __fmul_rn(dz, dz));
}

// ---- DPP wave-64 reduction steps (idempotent ops -> full masks safe) ----
template <int CTRL>
__device__ __forceinline__ float dpp_fmax_step(float x) {
    int xi = __float_as_int(x);
    int yi = __builtin_amdgcn_update_dpp(xi, xi, CTRL, 0xf, 0xf, false);
    return fmaxf(x, __int_as_float(yi));
}
template <int CTRL>
__device__ __forceinline__ unsigned dpp_umin_step(unsigned x) {
    int xi = (int)x;
    unsigned y = (unsigned)__builtin_amdgcn_update_dpp(xi, xi, CTRL, 0xf, 0xf, false);
    return y < x ? y : x;
}
__device__ __forceinline__ unsigned wave_umin(unsigned x) {
    x = dpp_umin_step<0x111>(x);
    x = dpp_umin_step<0x112>(x);
    x = dpp_umin_step<0x114>(x);
    x = dpp_umin_step<0x118>(x);
    x = dpp_umin_step<0x142>(x);
    x = dpp_umin_step<0x143>(x);
    return (unsigned)__builtin_amdgcn_readlane((int)x, 63);
}

// ---------------------------------------------------------------------------
// Kernel 1: furthest point sampling. Single block, 1024 threads, 16 pts/thread
// as packed v2f32 pairs in registers. amdgpu_waves_per_eu(4,4) pins exactly
// 4 waves/EU -> 128-VGPR budget so the 64-float state stays in real VGPRs
// (R4: allocator targeted 64 VGPRs -> AGPR/scratch shuffling dominated).
// ---------------------------------------------------------------------------
__global__ __launch_bounds__(1024) __attribute__((amdgpu_waves_per_eu(4, 4)))
void fps_kernel(const float* __restrict__ p, float* __restrict__ out) {
#pragma clang fp contract(off)
    const int t = threadIdx.x;
    const int lane = t & 63, wv = t >> 6;
    __shared__ float s_wmax[2][16];
    __shared__ float s_cq[16][4];
    __shared__ unsigned long long s_key[2];

    v2f px[8], py[8], pz[8], d2[8];
    const float q0x = p[0], q0y = p[1], q0z = p[2];
    float bv = -1.0f;
#pragma unroll
    for (int u = 0; u < 8; ++u) {
        const int j0 = (2 * u) * 1024 + t;
        const int j1 = j0 + 1024;
        const float ax0 = p[3 * j0], ay0 = p[3 * j0 + 1], az0 = p[3 * j0 + 2];
        const float ax1 = p[3 * j1], ay1 = p[3 * j1 + 1], az1 = p[3 * j1 + 2];
        px[u] = (v2f){ax0, ax1};
        py[u] = (v2f){ay0, ay1};
        pz[u] = (v2f){az0, az1};
        d2[u] = (v2f){dist2_exact(ax0, ay0, az0, q0x, q0y, q0z),
                      dist2_exact(ax1, ay1, az1, q0x, q0y, q0z)};
        bv = fmaxf(bv, fmaxf(d2[u].x, d2[u].y));
    }
    if (t == 0) {
        out[0] = q0x; out[1] = q0y; out[2] = q0z;      // n_p[0] = p[0]
        out[12288 + 786432] = 4096.0f;                 // n_o scalar
        s_key[0] = 0ull; s_key[1] = 0ull;
    }

    for (int i = 1; i < M_PTS; ++i) {
        const int par = i & 1;
        // per-wave max of bv (6 DPP steps), lane63 -> sgpr broadcast
        float wval = bv;
        wval = dpp_fmax_step<0x111>(wval);
        wval = dpp_fmax_step<0x112>(wval);
        wval = dpp_fmax_step<0x114>(wval);
        wval = dpp_fmax_step<0x118>(wval);
        wval = dpp_fmax_step<0x142>(wval);
        wval = dpp_fmax_step<0x143>(wval);
        const float wmax_u = __int_as_float(__builtin_amdgcn_readlane(__float_as_int(wval), 63));
        if (lane == 63) s_wmax[par][wv] = wval;
        if (t == 0) s_key[1 - par] = 0ull;             // reset for NEXT iteration
        __syncthreads();                               // barrier 1

        // cross-wave value max: 16 floats, 4 row_shr steps within 16-lane rows
        float cv = s_wmax[par][lane & 15];
        cv = dpp_fmax_step<0x111>(cv);
        cv = dpp_fmax_step<0x112>(cv);
        cv = dpp_fmax_step<0x114>(cv);
        cv = dpp_fmax_step<0x118>(cv);
        const float vmax = __int_as_float(__builtin_amdgcn_readlane(__float_as_int(cv), 63));

        // lazy index + coord resolution: only wave(s) holding the global max.
        // ALL register indices below are compile-time (unrolled) — no scratch.
        if (wmax_u == vmax) {
            unsigned idx = 0x7fffffffu;
            float cqx = 0.0f, cqy = 0.0f, cqz = 0.0f;
#pragma unroll
            for (int u = 15; u >= 0; --u) {            // descending: smallest u wins
                const float dv = (u & 1) ? d2[u >> 1].y : d2[u >> 1].x;
                if (dv == vmax) {
                    idx = (unsigned)(u * 1024 + t);
                    cqx = (u & 1) ? px[u >> 1].y : px[u >> 1].x;
                    cqy = (u & 1) ? py[u >> 1].y : py[u >> 1].x;
                    cqz = (u & 1) ? pz[u >> 1].y : pz[u >> 1].x;
                }
            }
            const unsigned wmin = wave_umin(idx);
            if (idx == wmin) {                         // unique winner lane
                s_cq[wv][0] = cqx; s_cq[wv][1] = cqy; s_cq[wv][2] = cqz;
                const unsigned long long key =
                    ((unsigned long long)__float_as_uint(vmax) << 32) |
                    (unsigned long long)(~wmin);       // bigger key = smaller idx
                atomicMax(&s_key[par], key);
            }
        }
        __syncthreads();                               // barrier 2

        const unsigned wmin_g = ~((unsigned)s_key[par]);
        const int wwin = (int)((wmin_g & 1023u) >> 6);
        const float qx = s_cq[wwin][0];
        const float qy = s_cq[wwin][1];
        const float qz = s_cq[wwin][2];
        if (t == 0) { out[3 * i] = qx; out[3 * i + 1] = qy; out[3 * i + 2] = qz; }

        // packed min-update + fused running max
        const v2f qx2 = (v2f){qx, qx};
        const v2f qy2 = (v2f){qy, qy};
        const v2f qz2 = (v2f){qz, qz};
        bv = -1.0f;
#pragma unroll
        for (int u = 0; u < 8; ++u) {
            const v2f dx = px[u] - qx2;
            const v2f dy = py[u] - qy2;
            const v2f dz = pz[u] - qz2;
            const v2f m1 = dx * dx;
            const v2f m2 = dy * dy;
            const v2f m3 = dz * dz;
            const v2f s = (m1 + m2) + m3;              // contract(off): matches reference
            d2[u] = __builtin_elementwise_min(d2[u], s);
            bv = fmaxf(bv, fmaxf(d2[u].x, d2[u].y));
        }
    }
}

// ---------------------------------------------------------------------------
// Kernel 2: kNN (k=16) of each n_p among p. One wave per query, per-lane sorted
// top-16 in registers, lexicographic (d, idx) wave merge (matches top_k ties).
// ---------------------------------------------------------------------------
__global__ __launch_bounds__(256) void knn_kernel(const float* __restrict__ p,
                                                  const float* __restrict__ np_,
                                                  int* __restrict__ nn) {
    const int lane = threadIdx.x & 63;
    const int m = (blockIdx.x * 256 + threadIdx.x) >> 6;
    if (m >= M_PTS) return;

    const float qx = np_[3 * m], qy = np_[3 * m + 1], qz = np_[3 * m + 2];
    const float qq = __fadd_rn(__fadd_rn(__fmul_rn(qx, qx), __fmul_rn(qy, qy)),
                               __fmul_rn(qz, qz));
    float D[16]; int I[16];
#pragma unroll
    for (int s = 0; s < 16; ++s) { D[s] = FLT_MAX; I[s] = 0x7fffffff; }

    for (int c = 0; c < N_PTS / 64; ++c) {
        const int j = c * 64 + lane;
        const float px = p[3 * j], py = p[3 * j + 1], pz = p[3 * j + 2];
        const float pp = __fadd_rn(__fadd_rn(__fmul_rn(px, px), __fmul_rn(py, py)),
                                   __fmul_rn(pz, pz));
        const float qp = __fadd_rn(__fadd_rn(__fmul_rn(qx, px), __fmul_rn(qy, py)),
                                   __fmul_rn(qz, pz));
        const float d = __fadd_rn(__fsub_rn(qq, __fmul_rn(2.0f, qp)), pp);
        if (d < D[15]) {
            D[15] = d; I[15] = j;
#pragma unroll
            for (int s = 15; s > 0; --s) {
                if (D[s] < D[s - 1]) {
                    float tf = D[s]; D[s] = D[s - 1]; D[s - 1] = tf;
                    int   ti = I[s]; I[s] = I[s - 1]; I[s - 1] = ti;
                }
            }
        }
    }

    int myout = 0;
    for (int r = 0; r < 16; ++r) {
        float v = D[0]; int ix = I[0]; int bl = lane;
#pragma unroll
        for (int off = 1; off < 64; off <<= 1) {
            float ov = __shfl_xor(v, off);
            int   oi = __shfl_xor(ix, off);
            int   ol = __shfl_xor(bl, off);
            if (ov < v || (ov == v && oi < ix)) { v = ov; ix = oi; bl = ol; }
        }
        if (lane == bl) {
#pragma unroll
            for (int s = 0; s < 15; ++s) { D[s] = D[s + 1]; I[s] = I[s + 1]; }
            D[15] = FLT_MAX; I[15] = 0x7fffffff;
        }
        if (lane == r) myout = ix;
    }
    if (lane < K_NN) nn[m * K_NN + lane] = myout;
}

// ---------------------------------------------------------------------------
// Kernel 3: grouped VNLinearLeakyReLU + mean over nsample.
// One block per query m. W_feat/W_dir staged transposed in LDS; thread (o,i)
// accumulates over k. out layout (Cout,3,M): out[(o*3+i)*M + m].
// ---------------------------------------------------------------------------
__global__ __launch_bounds__(256) void vn_kernel(const float* __restrict__ x,
                                                 const float* __restrict__ Wf,
                                                 const float* __restrict__ Wd,
                                                 const int* __restrict__ nn,
                                                 float* __restrict__ out) {
    __shared__ float sWf[CIN * COUT];
    __shared__ float sWd[CIN * COUT];
    __shared__ float sg[CIN * 3];
    __shared__ float sq[COUT * 3];
    __shared__ float sd[COUT * 3];
    __shared__ float sf[COUT];

    const int m = blockIdx.x;
    const int tid = threadIdx.x;
    for (int u = tid; u < CIN * COUT; u += 256) {
        const int o = u >> 6, c = u & 63;
        sWf[c * 64 + o] = Wf[u];
        sWd[c * 64 + o] = Wd[u];
    }
    const int o = tid & 63, i = tid >> 6;
    const bool active = tid < 192;
    float acc = 0.0f;

    for (int k = 0; k < K_NN; ++k) {
        __syncthreads();
        const int j = nn[m * K_NN + k];
        if (tid < 192) sg[tid] = x[j * 192 + tid];
        __syncthreads();
        float qv = 0.0f, dv = 0.0f;
        if (active) {
#pragma unroll
            for (int c = 0; c < CIN; ++c) {
                const float g = sg[c * 3 + i];
                qv = fmaf(sWf[c * 64 + o], g, qv);
                dv = fmaf(sWd[c * 64 + o], g, dv);
            }
            sq[o * 3 + i] = qv;
            sd[o * 3 + i] = dv;
        }
        __syncthreads();
        if (tid < 64) {
            const float d0 = sd[tid * 3], d1 = sd[tid * 3 + 1], d2v = sd[tid * 3 + 2];
            const float q0 = sq[tid * 3], q1 = sq[tid * 3 + 1], q2 = sq[tid * 3 + 2];
            const float dot = q0 * d0 + q1 * d1 + q2 * d2v;
            const float dns = d0 * d0 + d1 * d1 + d2v * d2v + 1e-6f;
            sf[tid] = (dot >= 0.0f) ? 0.0f : 0.8f * (dot / dns);
        }
        __syncthreads();
        if (active) acc += qv - sf[o] * dv;
    }
    if (active) out[(o * 3 + i) * M_PTS + m] = acc * 0.0625f;
}

// ---------------------------------------------------------------------------
extern "C" void kernel_launch(void* const* d_in, const int* in_sizes, int n_in,
                              void* d_out, int out_size, void* d_ws, size_t ws_size,
                              hipStream_t stream) {
    const float* p  = (const float*)d_in[0];
    const float* x  = (const float*)d_in[1];
    const float* Wf = (const float*)d_in[2];
    const float* Wd = (const float*)d_in[3];
    float* out = (float*)d_out;
    int* nn = (int*)d_ws;

    fps_kernel<<<1, 1024, 0, stream>>>(p, out);
    knn_kernel<<<M_PTS / 4, 256, 0, stream>>>(p, out, nn);
    vn_kernel<<<M_PTS, 256, 0, stream>>>(x, Wf, Wd, nn, out + 12288);
}

// Round 6
// 7639.222 us; speedup vs baseline: 2.2093x; 1.0528x over previous
//
#include <hip/hip_runtime.h>
#include <float.h>

#define N_PTS 16384
#define M_PTS 4096
#define K_NN  16
#define CIN   64
#define COUT  64

typedef float v2f __attribute__((ext_vector_type(2)));

// Exact f32 rounding to match numpy/jax: ((dx*dx + dy*dy) + dz*dz), no fma contraction.
__device__ __forceinline__ float dist2_exact(float ax, float ay, float az,
                                             float bx, float by, float bz) {
    float dx = __fsub_rn(ax, bx);
    float dy = __fsub_rn(ay, by);
    float dz = __fsub_rn(az, bz);
    return __fadd_rn(__fadd_rn(__fmul_rn(dx, dx), __fmul_rn(dy, dy)), __fmul_rn(dz, dz));
}

// ---- DPP wave-64 reduction steps (idempotent ops -> full masks safe) ----
template <int CTRL>
__device__ __forceinline__ float dpp_fmax_step(float x) {
    int xi = __float_as_int(x);
    int yi = __builtin_amdgcn_update_dpp(xi, xi, CTRL, 0xf, 0xf, false);
    return fmaxf(x, __int_as_float(yi));
}
template <int CTRL>
__device__ __forceinline__ unsigned dpp_umin_step(unsigned x) {
    int xi = (int)x;
    unsigned y = (unsigned)__builtin_amdgcn_update_dpp(xi, xi, CTRL, 0xf, 0xf, false);
    return y < x ? y : x;
}
__device__ __forceinline__ unsigned wave_umin(unsigned x) {
    x = dpp_umin_step<0x111>(x);
    x = dpp_umin_step<0x112>(x);
    x = dpp_umin_step<0x114>(x);
    x = dpp_umin_step<0x118>(x);
    x = dpp_umin_step<0x142>(x);
    x = dpp_umin_step<0x143>(x);
    return (unsigned)__builtin_amdgcn_readlane((int)x, 63);
}

// ---------------------------------------------------------------------------
// Kernel 1: furthest point sampling. Single block, 1024 threads, 16 pts/thread.
// Register state is ONLY z[8 pairs] + d2[8 pairs] (32 VGPRs) so it fits the
// allocator's stubborn 64-VGPR budget (R4/R5: bigger state -> AGPR shuffling).
// x,y live in LDS as float4 pairs, stride-9 padded (bank-spread, imm offsets).
// Points remapped thread-contiguously: j = t*16 + u (tie-break still original
// index order). Winner x,y fetched from LDS by the candidate lane (runtime
// LDS indexing is fine; only register runtime indexing spills).
// ---------------------------------------------------------------------------
__global__ __launch_bounds__(1024) void fps_kernel(const float* __restrict__ p,
                                                   float* __restrict__ out) {
#pragma clang fp contract(off)
    const int t = threadIdx.x;
    const int lane = t & 63, wv = t >> 6;
    __shared__ float4 s_xy4[1024 * 9];                 // 147456 B: [t*9 + pair]
    __shared__ float s_wmax[2][16];
    __shared__ float s_cq[16][4];
    __shared__ unsigned long long s_key[2];

    v2f zp[8], d2[8];
    const float q0x = p[0], q0y = p[1], q0z = p[2];
    float bv = -1.0f;
#pragma unroll
    for (int u = 0; u < 8; ++u) {
        const int j0 = t * 16 + 2 * u, j1 = j0 + 1;
        const float x0 = p[3 * j0], y0 = p[3 * j0 + 1], z0 = p[3 * j0 + 2];
        const float x1 = p[3 * j1], y1 = p[3 * j1 + 1], z1 = p[3 * j1 + 2];
        s_xy4[t * 9 + u] = make_float4(x0, y0, x1, y1);
        zp[u] = (v2f){z0, z1};
        d2[u] = (v2f){dist2_exact(x0, y0, z0, q0x, q0y, q0z),
                      dist2_exact(x1, y1, z1, q0x, q0y, q0z)};
        bv = fmaxf(bv, fmaxf(d2[u].x, d2[u].y));
    }
    if (t == 0) {
        out[0] = q0x; out[1] = q0y; out[2] = q0z;      // n_p[0] = p[0]
        out[12288 + 786432] = 4096.0f;                 // n_o scalar
        s_key[0] = 0ull; s_key[1] = 0ull;
    }

    for (int i = 1; i < M_PTS; ++i) {
        const int par = i & 1;
        // per-wave max of bv (6 DPP steps), lane63 -> sgpr broadcast
        float wval = bv;
        wval = dpp_fmax_step<0x111>(wval);
        wval = dpp_fmax_step<0x112>(wval);
        wval = dpp_fmax_step<0x114>(wval);
        wval = dpp_fmax_step<0x118>(wval);
        wval = dpp_fmax_step<0x142>(wval);
        wval = dpp_fmax_step<0x143>(wval);
        const float wmax_u = __int_as_float(__builtin_amdgcn_readlane(__float_as_int(wval), 63));
        if (lane == 63) s_wmax[par][wv] = wval;
        if (t == 0) s_key[1 - par] = 0ull;             // reset for NEXT iteration
        __syncthreads();                               // barrier 1

        // cross-wave value max: 16 floats, 4 row_shr steps within 16-lane rows
        float cv = s_wmax[par][lane & 15];
        cv = dpp_fmax_step<0x111>(cv);
        cv = dpp_fmax_step<0x112>(cv);
        cv = dpp_fmax_step<0x114>(cv);
        cv = dpp_fmax_step<0x118>(cv);
        const float vmax = __int_as_float(__builtin_amdgcn_readlane(__float_as_int(cv), 63));

        // lazy index resolution: only wave(s) holding the global max.
        // d2/z scanned with compile-time indices; x,y fetched from LDS.
        if (wmax_u == vmax) {
            unsigned idx = 0x7fffffffu;
            float cqz = 0.0f;
#pragma unroll
            for (int u = 15; u >= 0; --u) {            // descending: smallest u wins
                const float dv = (u & 1) ? d2[u >> 1].y : d2[u >> 1].x;
                if (dv == vmax) {
                    idx = (unsigned)(t * 16 + u);
                    cqz = (u & 1) ? zp[u >> 1].y : zp[u >> 1].x;
                }
            }
            const unsigned wmin = wave_umin(idx);
            if (idx == wmin) {                         // unique winner lane
                const int up = (int)(wmin & 15u);
                const float2* f2 = (const float2*)&s_xy4[t * 9 + (up >> 1)];
                const float2 xy = f2[up & 1];
                s_cq[wv][0] = xy.x; s_cq[wv][1] = xy.y; s_cq[wv][2] = cqz;
                const unsigned long long key =
                    ((unsigned long long)__float_as_uint(vmax) << 32) |
                    (unsigned long long)(~wmin);       // bigger key = smaller idx
                atomicMax(&s_key[par], key);
            }
        }
        __syncthreads();                               // barrier 2

        const unsigned wmin_g = ~((unsigned)s_key[par]);
        const int wwin = (int)((wmin_g >> 10) & 15u);  // winner wave (idx>>4 = t, t>>6)
        float qx = s_cq[wwin][0];
        float qy = s_cq[wwin][1];
        float qz = s_cq[wwin][2];
        if (t == 0) { out[3 * i] = qx; out[3 * i + 1] = qy; out[3 * i + 2] = qz; }
        // wave-uniform -> SGPR so packed ops use sgpr srcs (frees VGPRs)
        qx = __int_as_float(__builtin_amdgcn_readfirstlane(__float_as_int(qx)));
        qy = __int_as_float(__builtin_amdgcn_readfirstlane(__float_as_int(qy)));
        qz = __int_as_float(__builtin_amdgcn_readfirstlane(__float_as_int(qz)));
        const v2f qx2 = (v2f){qx, qx};
        const v2f qy2 = (v2f){qy, qy};
        const v2f qz2 = (v2f){qz, qz};

        // packed min-update: x,y streamed from LDS (b128, imm offsets), z/d2 regs
        bv = -1.0f;
#pragma unroll
        for (int u = 0; u < 8; ++u) {
            const float4 xy = s_xy4[t * 9 + u];
            const v2f xp = (v2f){xy.x, xy.z};
            const v2f yp = (v2f){xy.y, xy.w};
            const v2f dx = xp - qx2;
            const v2f dy = yp - qy2;
            const v2f dz = zp[u] - qz2;
            const v2f m1 = dx * dx;
            const v2f m2 = dy * dy;
            const v2f m3 = dz * dz;
            const v2f s = (m1 + m2) + m3;              // contract(off): matches reference
            d2[u] = __builtin_elementwise_min(d2[u], s);
            bv = fmaxf(bv, fmaxf(d2[u].x, d2[u].y));
        }
    }
}

// ---------------------------------------------------------------------------
// Kernel 2: kNN (k=16) of each n_p among p. One wave per query, per-lane sorted
// top-16 in registers, lexicographic (d, idx) wave merge (matches top_k ties).
// ---------------------------------------------------------------------------
__global__ __launch_bounds__(256) void knn_kernel(const float* __restrict__ p,
                                                  const float* __restrict__ np_,
                                                  int* __restrict__ nn) {
    const int lane = threadIdx.x & 63;
    const int m = (blockIdx.x * 256 + threadIdx.x) >> 6;
    if (m >= M_PTS) return;

    const float qx = np_[3 * m], qy = np_[3 * m + 1], qz = np_[3 * m + 2];
    const float qq = __fadd_rn(__fadd_rn(__fmul_rn(qx, qx), __fmul_rn(qy, qy)),
                               __fmul_rn(qz, qz));
    float D[16]; int I[16];
#pragma unroll
    for (int s = 0; s < 16; ++s) { D[s] = FLT_MAX; I[s] = 0x7fffffff; }

    for (int c = 0; c < N_PTS / 64; ++c) {
        const int j = c * 64 + lane;
        const float px = p[3 * j], py = p[3 * j + 1], pz = p[3 * j + 2];
        const float pp = __fadd_rn(__fadd_rn(__fmul_rn(px, px), __fmul_rn(py, py)),
                                   __fmul_rn(pz, pz));
        const float qp = __fadd_rn(__fadd_rn(__fmul_rn(qx, px), __fmul_rn(qy, py)),
                                   __fmul_rn(qz, pz));
        const float d = __fadd_rn(__fsub_rn(qq, __fmul_rn(2.0f, qp)), pp);
        if (d < D[15]) {
            D[15] = d; I[15] = j;
#pragma unroll
            for (int s = 15; s > 0; --s) {
                if (D[s] < D[s - 1]) {
                    float tf = D[s]; D[s] = D[s - 1]; D[s - 1] = tf;
                    int   ti = I[s]; I[s] = I[s - 1]; I[s - 1] = ti;
                }
            }
        }
    }

    int myout = 0;
    for (int r = 0; r < 16; ++r) {
        float v = D[0]; int ix = I[0]; int bl = lane;
#pragma unroll
        for (int off = 1; off < 64; off <<= 1) {
            float ov = __shfl_xor(v, off);
            int   oi = __shfl_xor(ix, off);
            int   ol = __shfl_xor(bl, off);
            if (ov < v || (ov == v && oi < ix)) { v = ov; ix = oi; bl = ol; }
        }
        if (lane == bl) {
#pragma unroll
            for (int s = 0; s < 15; ++s) { D[s] = D[s + 1]; I[s] = I[s + 1]; }
            D[15] = FLT_MAX; I[15] = 0x7fffffff;
        }
        if (lane == r) myout = ix;
    }
    if (lane < K_NN) nn[m * K_NN + lane] = myout;
}

// ---------------------------------------------------------------------------
// Kernel 3: grouped VNLinearLeakyReLU + mean over nsample.
// One block per query m. W_feat/W_dir staged transposed in LDS; thread (o,i)
// accumulates over k. out layout (Cout,3,M): out[(o*3+i)*M + m].
// ---------------------------------------------------------------------------
__global__ __launch_bounds__(256) void vn_kernel(const float* __restrict__ x,
                                                 const float* __restrict__ Wf,
                                                 const float* __restrict__ Wd,
                                                 const int* __restrict__ nn,
                                                 float* __restrict__ out) {
    __shared__ float sWf[CIN * COUT];
    __shared__ float sWd[CIN * COUT];
    __shared__ float sg[CIN * 3];
    __shared__ float sq[COUT * 3];
    __shared__ float sd[COUT * 3];
    __shared__ float sf[COUT];

    const int m = blockIdx.x;
    const int tid = threadIdx.x;
    for (int u = tid; u < CIN * COUT; u += 256) {
        const int o = u >> 6, c = u & 63;
        sWf[c * 64 + o] = Wf[u];
        sWd[c * 64 + o] = Wd[u];
    }
    const int o = tid & 63, i = tid >> 6;
    const bool active = tid < 192;
    float acc = 0.0f;

    for (int k = 0; k < K_NN; ++k) {
        __syncthreads();
        const int j = nn[m * K_NN + k];
        if (tid < 192) sg[tid] = x[j * 192 + tid];
        __syncthreads();
        float qv = 0.0f, dv = 0.0f;
        if (active) {
#pragma unroll
            for (int c = 0; c < CIN; ++c) {
                const float g = sg[c * 3 + i];
                qv = fmaf(sWf[c * 64 + o], g, qv);
                dv = fmaf(sWd[c * 64 + o], g, dv);
            }
            sq[o * 3 + i] = qv;
            sd[o * 3 + i] = dv;
        }
        __syncthreads();
        if (tid < 64) {
            const float d0 = sd[tid * 3], d1 = sd[tid * 3 + 1], d2v = sd[tid * 3 + 2];
            const float q0 = sq[tid * 3], q1 = sq[tid * 3 + 1], q2 = sq[tid * 3 + 2];
            const float dot = q0 * d0 + q1 * d1 + q2 * d2v;
            const float dns = d0 * d0 + d1 * d1 + d2v * d2v + 1e-6f;
            sf[tid] = (dot >= 0.0f) ? 0.0f : 0.8f * (dot / dns);
        }
        __syncthreads();
        if (active) acc += qv - sf[o] * dv;
    }
    if (active) out[(o * 3 + i) * M_PTS + m] = acc * 0.0625f;
}

// ---------------------------------------------------------------------------
extern "C" void kernel_launch(void* const* d_in, const int* in_sizes, int n_in,
                              void* d_out, int out_size, void* d_ws, size_t ws_size,
                              hipStream_t stream) {
    const float* p  = (const float*)d_in[0];
    const float* x  = (const float*)d_in[1];
    const float* Wf = (const float*)d_in[2];
    const float* Wd = (const float*)d_in[3];
    float* out = (float*)d_out;
    int* nn = (int*)d_ws;

    fps_kernel<<<1, 1024, 0, stream>>>(p, out);
    knn_kernel<<<M_PTS / 4, 256, 0, stream>>>(p, out, nn);
    vn_kernel<<<M_PTS, 256, 0, stream>>>(x, Wf, Wd, nn, out + 12288);
}

// Round 7
// 6000.130 us; speedup vs baseline: 2.8128x; 1.2732x over previous
//
#include <hip/hip_runtime.h>
#include <float.h>

#define N_PTS 16384
#define M_PTS 4096
#define K_NN  16
#define CIN   64
#define COUT  64

typedef float v2f __attribute__((ext_vector_type(2)));
typedef unsigned long long ull;

// Exact f32 rounding to match numpy/jax: ((dx*dx + dy*dy) + dz*dz), no fma contraction.
__device__ __forceinline__ float dist2_exact(float ax, float ay, float az,
                                             float bx, float by, float bz) {
    float dx = __fsub_rn(ax, bx);
    float dy = __fsub_rn(ay, by);
    float dz = __fsub_rn(az, bz);
    return __fadd_rn(__fadd_rn(__fmul_rn(dx, dx), __fmul_rn(dy, dy)), __fmul_rn(dz, dz));
}

// Packed f32 ops via inline asm (v2f codegen otherwise scalarizes — R6 evidence).
// pk_add with a pre-negated operand == exact subtraction (negation is exact).
__device__ __forceinline__ v2f pk_add(v2f a, v2f b) {
    v2f d; asm("v_pk_add_f32 %0, %1, %2" : "=v"(d) : "v"(a), "v"(b)); return d;
}
__device__ __forceinline__ v2f pk_mul(v2f a, v2f b) {
    v2f d; asm("v_pk_mul_f32 %0, %1, %2" : "=v"(d) : "v"(a), "v"(b)); return d;
}

// ---- DPP wave-64 reduction steps (idempotent ops -> full masks safe) ----
template <int CTRL>
__device__ __forceinline__ float dpp_fmax_step(float x) {
    int xi = __float_as_int(x);
    int yi = __builtin_amdgcn_update_dpp(xi, xi, CTRL, 0xf, 0xf, false);
    return fmaxf(x, __int_as_float(yi));
}
template <int CTRL>
__device__ __forceinline__ unsigned dpp_umin_step(unsigned x) {
    int xi = (int)x;
    unsigned y = (unsigned)__builtin_amdgcn_update_dpp(xi, xi, CTRL, 0xf, 0xf, false);
    return y < x ? y : x;
}
__device__ __forceinline__ unsigned wave_umin(unsigned x) {
    x = dpp_umin_step<0x111>(x);
    x = dpp_umin_step<0x112>(x);
    x = dpp_umin_step<0x114>(x);
    x = dpp_umin_step<0x118>(x);
    x = dpp_umin_step<0x142>(x);
    x = dpp_umin_step<0x143>(x);
    return (unsigned)__builtin_amdgcn_readlane((int)x, 63);
}

// ---------------------------------------------------------------------------
// Kernel 1: furthest point sampling with x-slab wave pruning.
// Phase A: bitonic x-sort of (x_bits<<32|idx) keys in LDS (one-time).
// Phase B: per-iter, a wave whose x-slab satisfies (|qx-cx|-hw)^2 > max(d2)
// provably has all-no-op updates -> s_cbranch skips the whole update loop.
// The skip threshold is the wave max already computed for the argmax.
// Tie-break by ORIGINAL index (packed u16 pairs, static-unroll access).
// ---------------------------------------------------------------------------
__global__ __launch_bounds__(1024) void fps_kernel(const float* __restrict__ p,
                                                   float* __restrict__ out) {
#pragma clang fp contract(off)
    const int t = threadIdx.x;
    const int lane = t & 63, wv = t >> 6;
    __shared__ char smem[147456];                      // keys[16384] then s_xy4[1024*9]
    __shared__ float s_wmax[2][16];
    __shared__ float s_cq[16][4];
    __shared__ ull s_key[2];

    ull* keys = (ull*)smem;
    float4* s_xy4 = (float4*)smem;

    // ---- Phase A: bitonic sort by x (keys unique via idx bits) ----
    for (int u = 0; u < 16; ++u) {
        const int j = u * 1024 + t;
        keys[j] = ((ull)__float_as_uint(p[3 * j]) << 32) | (unsigned)j;
    }
    __syncthreads();
    for (int k = 2; k <= N_PTS; k <<= 1) {
        for (int j = k >> 1; j > 0; j >>= 1) {
            for (int e = 0; e < 8; ++e) {
                const int c = e * 1024 + t;
                const int i1 = 2 * c - (c & (j - 1));
                const int i2 = i1 + j;
                const ull a = keys[i1], b = keys[i2];
                const bool up = ((i1 & k) == 0);
                if ((a > b) == up) { keys[i1] = b; keys[i2] = a; }
            }
            __syncthreads();
        }
    }

    // read own 16 sorted keys -> packed original indices (8 regs)
    unsigned opk[8];
#pragma unroll
    for (int u = 0; u < 8; ++u) {
        const ull a = keys[t * 16 + 2 * u];
        const ull b = keys[t * 16 + 2 * u + 1];
        opk[u] = ((unsigned)a & 0xffffu) | (((unsigned)b & 0xffffu) << 16);
    }
    __syncthreads();                                   // all key reads done before overwrite

    // ---- gather coords, build LDS xy ({x0,x1,y0,y1}) + reg z/d2, init bv ----
    v2f zp[8], d2[8];
    const float q0x = p[0], q0y = p[1], q0z = p[2];
    float bv = -1.0f;
    float xf = 0.0f, xl = 0.0f;
#pragma unroll
    for (int u = 0; u < 8; ++u) {
        const int o0 = (int)(opk[u] & 0xffffu), o1 = (int)(opk[u] >> 16);
        const float x0 = p[3 * o0], y0 = p[3 * o0 + 1], z0 = p[3 * o0 + 2];
        const float x1 = p[3 * o1], y1 = p[3 * o1 + 1], z1 = p[3 * o1 + 2];
        s_xy4[t * 9 + u] = make_float4(x0, x1, y0, y1);
        zp[u] = (v2f){z0, z1};
        d2[u] = (v2f){dist2_exact(x0, y0, z0, q0x, q0y, q0z),
                      dist2_exact(x1, y1, z1, q0x, q0y, q0z)};
        bv = fmaxf(bv, fmaxf(d2[u].x, d2[u].y));
        if (u == 0) xf = x0;
        if (u == 7) xl = x1;
    }
    // wave x-slab bounds (sorted ascending: lane0/slot0 = min, lane63/slot15 = max)
    const float wxmin = __int_as_float(__builtin_amdgcn_readlane(__float_as_int(xf), 0));
    const float wxmax = __int_as_float(__builtin_amdgcn_readlane(__float_as_int(xl), 63));
    const float cx = 0.5f * (wxmin + wxmax);
    const float hw_safe = 0.5f * (wxmax - wxmin) + 1e-5f;   // slack >> fp32 rounding

    if (t == 0) {
        out[0] = q0x; out[1] = q0y; out[2] = q0z;      // n_p[0] = p[0]
        out[12288 + 786432] = 4096.0f;                 // n_o scalar
        s_key[0] = 0ull; s_key[1] = 0ull;
    }

    for (int i = 1; i < M_PTS; ++i) {
        const int par = i & 1;
        // per-wave max of bv (6 DPP steps), lane63 -> sgpr broadcast
        float wval = bv;
        wval = dpp_fmax_step<0x111>(wval);
        wval = dpp_fmax_step<0x112>(wval);
        wval = dpp_fmax_step<0x114>(wval);
        wval = dpp_fmax_step<0x118>(wval);
        wval = dpp_fmax_step<0x142>(wval);
        wval = dpp_fmax_step<0x143>(wval);
        const float wmax_u = __int_as_float(__builtin_amdgcn_readlane(__float_as_int(wval), 63));
        if (lane == 63) s_wmax[par][wv] = wval;
        if (t == 0) s_key[1 - par] = 0ull;             // reset for NEXT iteration
        __syncthreads();                               // barrier 1

        // cross-wave value max: 16 floats, 4 row_shr steps within 16-lane rows
        float cv = s_wmax[par][lane & 15];
        cv = dpp_fmax_step<0x111>(cv);
        cv = dpp_fmax_step<0x112>(cv);
        cv = dpp_fmax_step<0x114>(cv);
        cv = dpp_fmax_step<0x118>(cv);
        const float vmax = __int_as_float(__builtin_amdgcn_readlane(__float_as_int(cv), 63));

        // lazy resolution: only wave(s) holding the global max. Tie-break on
        // ORIGINAL index. Register arrays indexed only by unrolled constants.
        if (wmax_u == vmax) {
            unsigned borig = 0xffffu;
            unsigned bslot = 0;
            float cqz = 0.0f;
#pragma unroll
            for (int u = 0; u < 16; ++u) {
                const float dv = (u & 1) ? d2[u >> 1].y : d2[u >> 1].x;
                const unsigned ou = (u & 1) ? (opk[u >> 1] >> 16) : (opk[u >> 1] & 0xffffu);
                if (dv == vmax && ou < borig) {
                    borig = ou;
                    bslot = (unsigned)u;
                    cqz = (u & 1) ? zp[u >> 1].y : zp[u >> 1].x;
                }
            }
            const unsigned wmin = wave_umin((borig << 6) | (unsigned)lane);
            if ((wmin & 63u) == (unsigned)lane && borig != 0xffffu) {
                // winner lane: xy from own LDS region (runtime LDS addr is fine)
                const float4 xy = s_xy4[t * 9 + (bslot >> 1)];
                const float qx = (bslot & 1) ? xy.y : xy.x;
                const float qy = (bslot & 1) ? xy.w : xy.z;
                s_cq[wv][0] = qx; s_cq[wv][1] = qy; s_cq[wv][2] = cqz;
                const ull key = ((ull)__float_as_uint(vmax) << 32) |
                                (ull)(~((borig << 4) | (unsigned)wv));
                atomicMax(&s_key[par], key);
            }
        }
        __syncthreads();                               // barrier 2

        const unsigned packed = ~((unsigned)s_key[par]);
        const int wwin = (int)(packed & 15u);
        float qx = s_cq[wwin][0];
        float qy = s_cq[wwin][1];
        float qz = s_cq[wwin][2];
        if (t == 0) { out[3 * i] = qx; out[3 * i + 1] = qy; out[3 * i + 2] = qz; }
        qx = __int_as_float(__builtin_amdgcn_readfirstlane(__float_as_int(qx)));
        qy = __int_as_float(__builtin_amdgcn_readfirstlane(__float_as_int(qy)));
        qz = __int_as_float(__builtin_amdgcn_readfirstlane(__float_as_int(qz)));

        // ---- wave-level slab prune: skip update iff provably all no-ops ----
        const float dxq = fabsf(qx - cx);
        bool active = true;
        if (dxq > hw_safe) {
            const float lb = dxq - hw_safe;            // conservative lower bound
            active = (lb * lb <= wmax_u);
        }
        if (active) {
            const v2f nqx2 = (v2f){-qx, -qx};
            const v2f nqy2 = (v2f){-qy, -qy};
            const v2f nqz2 = (v2f){-qz, -qz};
            bv = -1.0f;
#pragma unroll
            for (int u = 0; u < 8; ++u) {
                const float4 xy = s_xy4[t * 9 + u];
                const v2f xp = (v2f){xy.x, xy.y};      // {x0,x1} — no repack
                const v2f yp = (v2f){xy.z, xy.w};      // {y0,y1}
                const v2f dx = pk_add(xp, nqx2);       // exact x - qx
                const v2f dy = pk_add(yp, nqy2);
                const v2f dz = pk_add(zp[u], nqz2);
                const v2f m1 = pk_mul(dx, dx);
                const v2f m2 = pk_mul(dy, dy);
                const v2f m3 = pk_mul(dz, dz);
                const v2f s = pk_add(pk_add(m1, m2), m3);  // ((x²+y²)+z²) exact order
                d2[u] = __builtin_elementwise_min(d2[u], s);
                bv = fmaxf(bv, fmaxf(d2[u].x, d2[u].y));
            }
        }
    }
}

// ---------------------------------------------------------------------------
// Kernel 2: kNN (k=16) of each n_p among p. One wave per query, per-lane sorted
// top-16 in registers, lexicographic (d, idx) wave merge (matches top_k ties).
// ---------------------------------------------------------------------------
__global__ __launch_bounds__(256) void knn_kernel(const float* __restrict__ p,
                                                  const float* __restrict__ np_,
                                                  int* __restrict__ nn) {
    const int lane = threadIdx.x & 63;
    const int m = (blockIdx.x * 256 + threadIdx.x) >> 6;
    if (m >= M_PTS) return;

    const float qx = np_[3 * m], qy = np_[3 * m + 1], qz = np_[3 * m + 2];
    const float qq = __fadd_rn(__fadd_rn(__fmul_rn(qx, qx), __fmul_rn(qy, qy)),
                               __fmul_rn(qz, qz));
    float D[16]; int I[16];
#pragma unroll
    for (int s = 0; s < 16; ++s) { D[s] = FLT_MAX; I[s] = 0x7fffffff; }

    for (int c = 0; c < N_PTS / 64; ++c) {
        const int j = c * 64 + lane;
        const float px = p[3 * j], py = p[3 * j + 1], pz = p[3 * j + 2];
        const float pp = __fadd_rn(__fadd_rn(__fmul_rn(px, px), __fmul_rn(py, py)),
                                   __fmul_rn(pz, pz));
        const float qp = __fadd_rn(__fadd_rn(__fmul_rn(qx, px), __fmul_rn(qy, py)),
                                   __fmul_rn(qz, pz));
        const float d = __fadd_rn(__fsub_rn(qq, __fmul_rn(2.0f, qp)), pp);
        if (d < D[15]) {
            D[15] = d; I[15] = j;
#pragma unroll
            for (int s = 15; s > 0; --s) {
                if (D[s] < D[s - 1]) {
                    float tf = D[s]; D[s] = D[s - 1]; D[s - 1] = tf;
                    int   ti = I[s]; I[s] = I[s - 1]; I[s - 1] = ti;
                }
            }
        }
    }

    int myout = 0;
    for (int r = 0; r < 16; ++r) {
        float v = D[0]; int ix = I[0]; int bl = lane;
#pragma unroll
        for (int off = 1; off < 64; off <<= 1) {
            float ov = __shfl_xor(v, off);
            int   oi = __shfl_xor(ix, off);
            int   ol = __shfl_xor(bl, off);
            if (ov < v || (ov == v && oi < ix)) { v = ov; ix = oi; bl = ol; }
        }
        if (lane == bl) {
#pragma unroll
            for (int s = 0; s < 15; ++s) { D[s] = D[s + 1]; I[s] = I[s + 1]; }
            D[15] = FLT_MAX; I[15] = 0x7fffffff;
        }
        if (lane == r) myout = ix;
    }
    if (lane < K_NN) nn[m * K_NN + lane] = myout;
}

// ---------------------------------------------------------------------------
// Kernel 3: grouped VNLinearLeakyReLU + mean over nsample.
// One block per query m. W_feat/W_dir staged transposed in LDS; thread (o,i)
// accumulates over k. out layout (Cout,3,M): out[(o*3+i)*M + m].
// ---------------------------------------------------------------------------
__global__ __launch_bounds__(256) void vn_kernel(const float* __restrict__ x,
                                                 const float* __restrict__ Wf,
                                                 const float* __restrict__ Wd,
                                                 const int* __restrict__ nn,
                                                 float* __restrict__ out) {
    __shared__ float sWf[CIN * COUT];
    __shared__ float sWd[CIN * COUT];
    __shared__ float sg[CIN * 3];
    __shared__ float sq[COUT * 3];
    __shared__ float sd[COUT * 3];
    __shared__ float sf[COUT];

    const int m = blockIdx.x;
    const int tid = threadIdx.x;
    for (int u = tid; u < CIN * COUT; u += 256) {
        const int o = u >> 6, c = u & 63;
        sWf[c * 64 + o] = Wf[u];
        sWd[c * 64 + o] = Wd[u];
    }
    const int o = tid & 63, i = tid >> 6;
    const bool active = tid < 192;
    float acc = 0.0f;

    for (int k = 0; k < K_NN; ++k) {
        __syncthreads();
        const int j = nn[m * K_NN + k];
        if (tid < 192) sg[tid] = x[j * 192 + tid];
        __syncthreads();
        float qv = 0.0f, dv = 0.0f;
        if (active) {
#pragma unroll
            for (int c = 0; c < CIN; ++c) {
                const float g = sg[c * 3 + i];
                qv = fmaf(sWf[c * 64 + o], g, qv);
                dv = fmaf(sWd[c * 64 + o], g, dv);
            }
            sq[o * 3 + i] = qv;
            sd[o * 3 + i] = dv;
        }
        __syncthreads();
        if (tid < 64) {
            const float d0 = sd[tid * 3], d1 = sd[tid * 3 + 1], d2v = sd[tid * 3 + 2];
            const float q0 = sq[tid * 3], q1 = sq[tid * 3 + 1], q2 = sq[tid * 3 + 2];
            const float dot = q0 * d0 + q1 * d1 + q2 * d2v;
            const float dns = d0 * d0 + d1 * d1 + d2v * d2v + 1e-6f;
            sf[tid] = (dot >= 0.0f) ? 0.0f : 0.8f * (dot / dns);
        }
        __syncthreads();
        if (active) acc += qv - sf[o] * dv;
    }
    if (active) out[(o * 3 + i) * M_PTS + m] = acc * 0.0625f;
}

// ---------------------------------------------------------------------------
extern "C" void kernel_launch(void* const* d_in, const int* in_sizes, int n_in,
                              void* d_out, int out_size, void* d_ws, size_t ws_size,
                              hipStream_t stream) {
    const float* p  = (const float*)d_in[0];
    const float* x  = (const float*)d_in[1];
    const float* Wf = (const float*)d_in[2];
    const float* Wd = (const float*)d_in[3];
    float* out = (float*)d_out;
    int* nn = (int*)d_ws;

    fps_kernel<<<1, 1024, 0, stream>>>(p, out);
    knn_kernel<<<M_PTS / 4, 256, 0, stream>>>(p, out, nn);
    vn_kernel<<<M_PTS, 256, 0, stream>>>(x, Wf, Wd, nn, out + 12288);
}